// Round 3
// baseline (226.587 us; speedup 1.0000x reference)
//
#include <hip/hip_runtime.h>

// BezierSurfaceFitter, 2-kernel pipeline, register-preloaded B-fragments.
// out[bc,i,j] = sum_p Bu[i,p]*T[bc,p,j];  T[bc,p,j] = sum_q K[bc,p,q]*Bv[j,q]
// H=W=256, M=N=31 => Bu == Bv == one 256x32 Bernstein table.
//
// K1 (basis): Bu fp32 + bf16 hi/lo tables -> workspace (validated, 64 KB ws).
// K2 (main):  2 blocks per bc (half the i-range each). Phase 1 computes the
//   full T^T (all 256 j rows; thread tid owns row j=tid) into 32 KB LDS with
//   the validated chunk-XOR swizzle. Phase 2 PRELOADS all 16 B-fragments
//   (8 i-tiles x hi/lo) into registers, so the store loop is pure MFMA +
//   float4 stores: no loads => no s_waitcnt in the loop => stores are never
//   gated on prior-store acks (vmcnt FIFO coupling was the suspected 3x
//   over-floor cost). A-frags read once from LDS before the loop.
//   LDS 32 KB, ~130 VGPR => ~3 waves/SIMD, store port at high duty cycle.

#define DEG 31

typedef short bf16x8 __attribute__((ext_vector_type(8)));  // 8 bf16 in 4 VGPRs
typedef float f32x4  __attribute__((ext_vector_type(4)));

__device__ __forceinline__ unsigned short f2bf_rne(float x) {
    unsigned int u = __float_as_uint(x);
    unsigned int r = (u + 0x7FFFu + ((u >> 16) & 1u)) >> 16;
    return (unsigned short)r;
}
__device__ __forceinline__ float bf2f(unsigned short h) {
    return __uint_as_float(((unsigned int)h) << 16);
}

// ---- kernel 1: Bernstein basis tables (fp32 + bf16 hi/lo) ------------------
__global__ __launch_bounds__(256) void bez_basis_kernel(
        float* __restrict__ Bt,            // (256,32) fp32
        unsigned short* __restrict__ Hi,   // (256,32) bf16 hi
        unsigned short* __restrict__ Lo) { // (256,32) bf16 lo
    int g = blockIdx.x * 256 + threadIdx.x;   // 0..8191
    int i = g >> 5;
    int k = g & 31;
    double t = ((double)i + 0.5) / 256.0;
    double coeff = 1.0;                    // C(31,k), exact in fp64
    for (int kk = 1; kk <= k; ++kk)
        coeff = coeff * (double)(DEG - kk + 1) / (double)kk;
    double tk = 1.0;
    for (int e = 0; e < k; ++e) tk *= t;
    double omt = 1.0 - t;
    double tq = 1.0;
    for (int e = 0; e < DEG - k; ++e) tq *= omt;
    float v = (float)(coeff * tk * tq);
    Bt[g] = v;
    unsigned short h = f2bf_rne(v);
    Hi[g] = h;
    Lo[g] = f2bf_rne(v - bf2f(h));
}

// ---- kernel 2: main --------------------------------------------------------
__global__ __launch_bounds__(256) void bez_main_kernel(
        const float* __restrict__ K,             // (768,32,32) fp32
        const float* __restrict__ Bt,            // (256,32) fp32
        const unsigned short* __restrict__ Hi,   // (256,32) bf16 hi
        const unsigned short* __restrict__ Lo,   // (256,32) bf16 lo
        float* __restrict__ out) {               // (768,256,256) fp32
    // T^T rows as A-operand fragments, hi/lo. Row j: 32 bf16 (64 B), chunk
    // c (8 bf16, 16 B) stored at swizzled slot c ^ ((j>>1)&3).
    __shared__ __align__(16) unsigned short sThi[256 * 32];  // 16 KB
    __shared__ __align__(16) unsigned short sTlo[256 * 32];  // 16 KB

    const int bid  = blockIdx.x;        // 0..1535
    const int bc   = bid >> 1;          // 0..767
    const int half = bid & 1;           // which half of the i-range
    const int tid  = threadIdx.x;       // j in phase 1
    const int lane = tid & 63;
    const int w    = tid >> 6;          // wave 0..3

    // ------- phase 1: T^T row j=tid: T[p][tid] = sum_q K[bc,p,q]*Bt[tid,q] -
    float breg[32];
    const float4* brow = (const float4*)(Bt + tid * 32);
    #pragma unroll
    for (int q4 = 0; q4 < 8; ++q4) {
        float4 v = brow[q4];
        breg[q4 * 4 + 0] = v.x;
        breg[q4 * 4 + 1] = v.y;
        breg[q4 * 4 + 2] = v.z;
        breg[q4 * 4 + 3] = v.w;
    }
    const float* Kbc = K + (size_t)bc * 1024;   // wave-uniform -> s_load
    float treg[32];
    #pragma unroll
    for (int p = 0; p < 32; ++p) {
        float acc = 0.0f;
        #pragma unroll
        for (int qi = 0; qi < 32; ++qi)
            acc += Kbc[p * 32 + qi] * breg[qi];
        treg[p] = acc;
    }
    // split hi/lo, write A-fragment chunks (swizzled, conflict-free)
    const int jsw = (tid >> 1) & 3;
    #pragma unroll
    for (int c = 0; c < 4; ++c) {
        bf16x8 vh, vl;
        #pragma unroll
        for (int jj = 0; jj < 8; ++jj) {
            float x = treg[c * 8 + jj];
            unsigned short h = f2bf_rne(x);
            vh[jj] = (short)h;
            vl[jj] = (short)f2bf_rne(x - bf2f(h));
        }
        int off = tid * 32 + (c ^ jsw) * 8;
        *(bf16x8*)&sThi[off] = vh;
        *(bf16x8*)&sTlo[off] = vl;
    }
    __syncthreads();

    // ------- phase 2: D = T^T * Bu^T, tiles 16x16, K=32 (one MFMA k-step) ---
    const int m = lane & 15;     // i within column-tile / A row j within tile
    const int q = lane >> 4;     // k-chunk for A/B; row-quad for D

    // A-frags: T^T rows for this wave's 4 j-tiles (jt = 4w+a), from LDS.
    bf16x8 Th[4], Tl[4];
    #pragma unroll
    for (int a = 0; a < 4; ++a) {
        int j = (w * 4 + a) * 16 + m;
        int off = j * 32 + (q ^ ((j >> 1) & 3)) * 8;
        Th[a] = *(const bf16x8*)&sThi[off];
        Tl[a] = *(const bf16x8*)&sTlo[off];
    }

    // B-frag PRELOAD: all 8 i-tiles of this block's half, hi+lo (64 VGPRs,
    // statically indexed via full unroll). After this, the store loop has
    // zero loads => zero waitcnt => stores free-run.
    bf16x8 Bh8[8], Bl8[8];
    #pragma unroll
    for (int it8 = 0; it8 < 8; ++it8) {
        int i = (half * 8 + it8) * 16 + m;
        Bh8[it8] = *(const bf16x8*)(Hi + i * 32 + q * 8);
        Bl8[it8] = *(const bf16x8*)(Lo + i * 32 + q * 8);
    }

    float* outbc = out + (size_t)bc * 65536;
    #pragma unroll
    for (int it8 = 0; it8 < 8; ++it8) {
        int i = (half * 8 + it8) * 16 + m;
        #pragma unroll
        for (int a = 0; a < 4; ++a) {
            f32x4 acc = {0.0f, 0.0f, 0.0f, 0.0f};
            acc = __builtin_amdgcn_mfma_f32_16x16x32_bf16(Tl[a], Bh8[it8], acc, 0, 0, 0);
            acc = __builtin_amdgcn_mfma_f32_16x16x32_bf16(Th[a], Bl8[it8], acc, 0, 0, 0);
            acc = __builtin_amdgcn_mfma_f32_16x16x32_bf16(Th[a], Bh8[it8], acc, 0, 0, 0);
            // D[row=q*4+r][col=m]: row -> j (consecutive in r), col -> i.
            float4 o4 = {acc[0], acc[1], acc[2], acc[3]};
            float* o = outbc + (size_t)i * 256 + (w * 4 + a) * 16 + q * 4;
            *(float4*)o = o4;   // 16B/lane; wave = 16 rows x 64B segments
        }
    }
}

extern "C" void kernel_launch(void* const* d_in, const int* in_sizes, int n_in,
                              void* d_out, int out_size, void* d_ws, size_t ws_size,
                              hipStream_t stream) {
    // d_in[0] = x (ignored), d_in[1] = K_mat (768*32*32 fp32)
    const float* K = (const float*)d_in[1];
    char* ws = (char*)d_ws;
    float*          Bt = (float*)ws;                      // 32 KB
    unsigned short* Hi = (unsigned short*)(ws + 32768);   // 16 KB
    unsigned short* Lo = (unsigned short*)(ws + 49152);   // 16 KB
    float* out = (float*)d_out;

    bez_basis_kernel<<<dim3(32), dim3(256), 0, stream>>>(Bt, Hi, Lo);
    bez_main_kernel<<<dim3(1536), dim3(256), 0, stream>>>(K, Bt, Hi, Lo, out);
}

// Round 4
// 215.656 us; speedup vs baseline: 1.0507x; 1.0507x over previous
//
#include <hip/hip_runtime.h>

// BezierSurfaceFitter. R0 structure with ONE change: output stores go through
// an LDS transpose stage so every global store is a wave-contiguous 1 KB row
// (identical pattern to the harness fill that sustains 6.5 TB/s), instead of
// the MFMA C-layout's 16 x 64B scatter at 1 KB stride.
//
// out[bc,i,j] = sum_p Bu[i,p]*T[bc,p,j];  T[bc,p,j] = sum_q K[bc,p,q]*Bv[j,q]
// K1 (basis): Bu fp32 + bf16 hi/lo tables -> workspace (validated).
// K2 (main), per bc:
//   phase 1: thread tid computes T^T row j=tid (fp32 VALU) -> LDS, hi/lo bf16,
//            chunk-XOR swizzled (validated layout).
//   phase 2: per i-tile it: 12 MFMA -> f32x4 acc; acc -> LDS slab S[16][256]
//            (col XOR (row&7)<<2 swizzle: exactly 8 words/bank, minimal);
//            barrier; wave w stores rows {s*4+w} as contiguous 1 KB
//            global_store_dwordx4 sweeps; barrier. Slab reuses sThi (dead
//            after A-frags are register-resident). LDS stays 32 KB.

#define DEG 31

typedef short bf16x8 __attribute__((ext_vector_type(8)));  // 8 bf16 in 4 VGPRs
typedef float f32x4  __attribute__((ext_vector_type(4)));

__device__ __forceinline__ unsigned short f2bf_rne(float x) {
    unsigned int u = __float_as_uint(x);
    unsigned int r = (u + 0x7FFFu + ((u >> 16) & 1u)) >> 16;
    return (unsigned short)r;
}
__device__ __forceinline__ float bf2f(unsigned short h) {
    return __uint_as_float(((unsigned int)h) << 16);
}

// ---- kernel 1: Bernstein basis tables (fp32 + bf16 hi/lo) ------------------
__global__ __launch_bounds__(256) void bez_basis_kernel(
        float* __restrict__ Bt,            // (256,32) fp32
        unsigned short* __restrict__ Hi,   // (256,32) bf16 hi
        unsigned short* __restrict__ Lo) { // (256,32) bf16 lo
    int g = blockIdx.x * 256 + threadIdx.x;   // 0..8191
    int i = g >> 5;
    int k = g & 31;
    double t = ((double)i + 0.5) / 256.0;
    double coeff = 1.0;                    // C(31,k), exact in fp64
    for (int kk = 1; kk <= k; ++kk)
        coeff = coeff * (double)(DEG - kk + 1) / (double)kk;
    double tk = 1.0;
    for (int e = 0; e < k; ++e) tk *= t;
    double omt = 1.0 - t;
    double tq = 1.0;
    for (int e = 0; e < DEG - k; ++e) tq *= omt;
    float v = (float)(coeff * tk * tq);
    Bt[g] = v;
    unsigned short h = f2bf_rne(v);
    Hi[g] = h;
    Lo[g] = f2bf_rne(v - bf2f(h));
}

// ---- kernel 2: main --------------------------------------------------------
__global__ __launch_bounds__(256) void bez_main_kernel(
        const float* __restrict__ K,             // (768,32,32) fp32
        const float* __restrict__ Bt,            // (256,32) fp32
        const unsigned short* __restrict__ Hi,   // (256,32) bf16 hi
        const unsigned short* __restrict__ Lo,   // (256,32) bf16 lo
        float* __restrict__ out) {               // (768,256,256) fp32
    // T^T rows as A-operand fragments, hi/lo. Row j: 32 bf16 (64 B), chunk
    // c (8 bf16, 16 B) stored at swizzled slot c ^ ((j>>1)&3).
    __shared__ __align__(16) unsigned short sThi[256 * 32];  // 16 KB
    __shared__ __align__(16) unsigned short sTlo[256 * 32];  // 16 KB

    const int bc   = blockIdx.x;        // 0..767
    const int tid  = threadIdx.x;       // j in phase 1
    const int lane = tid & 63;
    const int w    = tid >> 6;          // wave 0..3

    // ------- phase 1: T[p][tid] = sum_q K[bc,p,q] * Bt[tid,q] (fp32 VALU) ---
    float breg[32];
    const float4* brow = (const float4*)(Bt + tid * 32);
    #pragma unroll
    for (int q4 = 0; q4 < 8; ++q4) {
        float4 v = brow[q4];
        breg[q4 * 4 + 0] = v.x;
        breg[q4 * 4 + 1] = v.y;
        breg[q4 * 4 + 2] = v.z;
        breg[q4 * 4 + 3] = v.w;
    }
    const float* Kbc = K + (size_t)bc * 1024;   // wave-uniform -> s_load
    float treg[32];
    #pragma unroll
    for (int p = 0; p < 32; ++p) {
        float acc = 0.0f;
        #pragma unroll
        for (int q = 0; q < 32; ++q)
            acc += Kbc[p * 32 + q] * breg[q];
        treg[p] = acc;
    }
    // split hi/lo, write A-fragment chunks (swizzled, conflict-free)
    const int jsw = (tid >> 1) & 3;
    #pragma unroll
    for (int c = 0; c < 4; ++c) {
        bf16x8 vh, vl;
        #pragma unroll
        for (int jj = 0; jj < 8; ++jj) {
            float x = treg[c * 8 + jj];
            unsigned short h = f2bf_rne(x);
            vh[jj] = (short)h;
            vl[jj] = (short)f2bf_rne(x - bf2f(h));
        }
        int off = tid * 32 + (c ^ jsw) * 8;
        *(bf16x8*)&sThi[off] = vh;
        *(bf16x8*)&sTlo[off] = vl;
    }
    __syncthreads();

    // ------- phase 2: D = T^T * Bu^T, tiles 16x16, K=32 (one MFMA k-step) ---
    const int m = lane & 15;     // i within column-tile / A row j within tile
    const int q = lane >> 4;     // k-chunk for A/B; row-quad for D

    // A-frags: T^T rows for this wave's 4 j-tiles (jt = 4w+a), from LDS.
    bf16x8 Th[4], Tl[4];
    #pragma unroll
    for (int a = 0; a < 4; ++a) {
        int j = (w * 4 + a) * 16 + m;
        int off = j * 32 + (q ^ ((j >> 1) & 3)) * 8;
        Th[a] = *(const bf16x8*)&sThi[off];
        Tl[a] = *(const bf16x8*)&sTlo[off];
    }
    __syncthreads();   // sThi becomes the f32 staging slab from here on

    float* stage = (float*)sThi;            // 16 KB = 16 rows x 256 f32
    float* outbc = out + (size_t)bc * 65536;

    // reader indices (wave-uniform row per sweep s: row = s*4 + w)
    const int rcol = lane * 4;              // 64 lanes x 16 B = 1 KB row

    for (int it = 0; it < 16; ++it) {
        int i = it * 16 + m;
        // B-frags: Bu row i, chunk q (global, 32KB table shared -> L1-hot)
        bf16x8 Bh = *(const bf16x8*)(Hi + i * 32 + q * 8);
        bf16x8 Bl = *(const bf16x8*)(Lo + i * 32 + q * 8);
        #pragma unroll
        for (int a = 0; a < 4; ++a) {
            f32x4 acc = {0.0f, 0.0f, 0.0f, 0.0f};
            acc = __builtin_amdgcn_mfma_f32_16x16x32_bf16(Tl[a], Bh, acc, 0, 0, 0);
            acc = __builtin_amdgcn_mfma_f32_16x16x32_bf16(Th[a], Bl, acc, 0, 0, 0);
            acc = __builtin_amdgcn_mfma_f32_16x16x32_bf16(Th[a], Bh, acc, 0, 0, 0);
            // D[row=q*4+r][col=m] -> slab S[row=m][col=(w*4+a)*16+q*4 + r]
            int colbase = (w * 4 + a) * 16 + q * 4;
            int word = m * 256 + (colbase ^ ((m & 7) << 2));  // bank-uniform
            f32x4* dst = (f32x4*)&stage[word];
            *dst = acc;
        }
        __syncthreads();   // slab complete
        // sweep: wave w stores rows {s*4+w}; each store = contiguous 1 KB row
        #pragma unroll
        for (int s = 0; s < 4; ++s) {
            int row  = s * 4 + w;                       // wave-uniform
            int word = row * 256 + (rcol ^ ((row & 7) << 2));
            f32x4 v = *(const f32x4*)&stage[word];
            float4 o4 = {v[0], v[1], v[2], v[3]};
            float* o = outbc + (size_t)(it * 16 + row) * 256 + rcol;
            *(float4*)o = o4;   // wave: 64 lanes x 16 B = one full output row
        }
        __syncthreads();   // WAR: slab free for next it
    }
}

extern "C" void kernel_launch(void* const* d_in, const int* in_sizes, int n_in,
                              void* d_out, int out_size, void* d_ws, size_t ws_size,
                              hipStream_t stream) {
    // d_in[0] = x (ignored), d_in[1] = K_mat (768*32*32 fp32)
    const float* K = (const float*)d_in[1];
    char* ws = (char*)d_ws;
    float*          Bt = (float*)ws;                      // 32 KB
    unsigned short* Hi = (unsigned short*)(ws + 32768);   // 16 KB
    unsigned short* Lo = (unsigned short*)(ws + 49152);   // 16 KB
    float* out = (float*)d_out;

    bez_basis_kernel<<<dim3(32), dim3(256), 0, stream>>>(Bt, Hi, Lo);
    bez_main_kernel<<<dim3(768), dim3(256), 0, stream>>>(K, Bt, Hi, Lo, out);
}